// Round 20
// baseline (212.238 us; speedup 1.0000x reference)
//
#include <hip/hip_runtime.h>
#include <hip/hip_cooperative_groups.h>

namespace cg = cooperative_groups;

#define PCONST 50
#define ECONST 2000
#define MCONST 64
#define NKEY   (PCONST * ECONST)          // 100000 keys per CSR
#define KPB    256                        // keys per bin
#define NBIN   ((NKEY + KPB - 1) / KPB)   // 391 bins per CSR
#define NBIN2  (2 * NBIN)                 // 782
#define BLOCK_THREADS 1024
#define GRID_BLOCKS   256                 // == CU count; 1 block/CU at 82KB LDS
#define SC_CHUNK   8192                   // facts per chunk = 8/thread -> 84B runs/bin
#define FPT    (SC_CHUNK / BLOCK_THREADS) // 8
#define CAP    6144                       // bin capacity (mean 5115, +14 sigma, fixed seed)
#define SEGSZ  20512                      // binsort per-quarter LDS segment bytes

typedef int ivec4 __attribute__((ext_vector_type(4)));   // nontemporal-store-compatible

// ---------------------------------------------------------------------------
// Fused persistent kernel: phase0 zero bincur | phase1 scatter | phase2
// binsort (4 virtual 256-thr groups/block) | phase3 query, separated by
// grid.sync(). Phase bodies are R19 verbatim modulo indexing. LDS is an
// 82KB byte arena overlaid per phase (phases separated by grid sync).
// ---------------------------------------------------------------------------
__global__ void __launch_bounds__(BLOCK_THREADS)
fused_kernel(const int* __restrict__ facts,
             const int* __restrict__ preds,
             const int* __restrict__ bound,
             const int* __restrict__ dir,
             int* __restrict__ bincur,
             unsigned* __restrict__ slab,
             unsigned* __restrict__ qtab,
             unsigned short* __restrict__ dataA,
             int* __restrict__ cand,
             int* __restrict__ valid,
             int F, int N) {
    cg::grid_group grid = cg::this_grid();
    __shared__ __align__(16) unsigned char smem[4 * SEGSZ];   // 82048 B

    int t   = threadIdx.x;
    int bid = blockIdx.x;

    // ---- phase 0: zero bin cursors ----
    for (int i = bid * BLOCK_THREADS + t; i < NBIN2; i += GRID_BLOCKS * BLOCK_THREADS)
        bincur[i] = 0;
    grid.sync();

    // ---- phase 1: two-pass block-sorted slab scatter (R14/R19 body) ----
    {
        unsigned* ordered = (unsigned*)smem;                 // 65536 B
        int* cnt   = (int*)(smem + 65536);                   // 782 ints
        int* lbase = cnt + NBIN2;
        int* cur   = lbase + NBIN2;
        int* base  = cur + NBIN2;
        int* wsum  = base + NBIN2;                           // 16 ints

        int nChunks = (F + SC_CHUNK - 1) / SC_CHUNK;
        for (int chunk = bid; chunk < nChunks; chunk += GRID_BLOCKS) {
            int blockStart = chunk * SC_CHUNK;
            int n = min(SC_CHUNK, F - blockStart);
            if (n <= 0) break;

            for (int i = t; i < NBIN2; i += BLOCK_THREADS) cnt[i] = 0;
            __syncthreads();

            int myBase = blockStart + t * FPT;
            int myN = F - myBase;
            myN = (myN < 0) ? 0 : ((myN > FPT) ? FPT : myN);

            unsigned vps[FPT], vpo[FPT];

            if (myN == FPT) {
                const int4* p = (const int4*)(facts + 3 * myBase);   // 16B-aligned
                int4 w0 = p[0], w1 = p[1], w2 = p[2], w3 = p[3], w4 = p[4], w5 = p[5];
                int kps, kpo;
                kps = w0.x * ECONST + w0.y; kpo = w0.x * ECONST + w0.z;
                vps[0] = ((unsigned)kps << 11) | (unsigned)w0.z;
                vpo[0] = ((unsigned)kpo << 11) | (unsigned)w0.y;
                atomicAdd(&cnt[kps >> 8], 1); atomicAdd(&cnt[NBIN + (kpo >> 8)], 1);
                kps = w0.w * ECONST + w1.x; kpo = w0.w * ECONST + w1.y;
                vps[1] = ((unsigned)kps << 11) | (unsigned)w1.y;
                vpo[1] = ((unsigned)kpo << 11) | (unsigned)w1.x;
                atomicAdd(&cnt[kps >> 8], 1); atomicAdd(&cnt[NBIN + (kpo >> 8)], 1);
                kps = w1.z * ECONST + w1.w; kpo = w1.z * ECONST + w2.x;
                vps[2] = ((unsigned)kps << 11) | (unsigned)w2.x;
                vpo[2] = ((unsigned)kpo << 11) | (unsigned)w1.w;
                atomicAdd(&cnt[kps >> 8], 1); atomicAdd(&cnt[NBIN + (kpo >> 8)], 1);
                kps = w2.y * ECONST + w2.z; kpo = w2.y * ECONST + w2.w;
                vps[3] = ((unsigned)kps << 11) | (unsigned)w2.w;
                vpo[3] = ((unsigned)kpo << 11) | (unsigned)w2.z;
                atomicAdd(&cnt[kps >> 8], 1); atomicAdd(&cnt[NBIN + (kpo >> 8)], 1);
                kps = w3.x * ECONST + w3.y; kpo = w3.x * ECONST + w3.z;
                vps[4] = ((unsigned)kps << 11) | (unsigned)w3.z;
                vpo[4] = ((unsigned)kpo << 11) | (unsigned)w3.y;
                atomicAdd(&cnt[kps >> 8], 1); atomicAdd(&cnt[NBIN + (kpo >> 8)], 1);
                kps = w3.w * ECONST + w4.x; kpo = w3.w * ECONST + w4.y;
                vps[5] = ((unsigned)kps << 11) | (unsigned)w4.y;
                vpo[5] = ((unsigned)kpo << 11) | (unsigned)w4.x;
                atomicAdd(&cnt[kps >> 8], 1); atomicAdd(&cnt[NBIN + (kpo >> 8)], 1);
                kps = w4.z * ECONST + w4.w; kpo = w4.z * ECONST + w5.x;
                vps[6] = ((unsigned)kps << 11) | (unsigned)w5.x;
                vpo[6] = ((unsigned)kpo << 11) | (unsigned)w4.w;
                atomicAdd(&cnt[kps >> 8], 1); atomicAdd(&cnt[NBIN + (kpo >> 8)], 1);
                kps = w5.y * ECONST + w5.z; kpo = w5.y * ECONST + w5.w;
                vps[7] = ((unsigned)kps << 11) | (unsigned)w5.w;
                vpo[7] = ((unsigned)kpo << 11) | (unsigned)w5.z;
                atomicAdd(&cnt[kps >> 8], 1); atomicAdd(&cnt[NBIN + (kpo >> 8)], 1);
            } else {
                for (int i = 0; i < myN; ++i) {
                    int g = myBase + i;
                    int fp = facts[3 * g], fs = facts[3 * g + 1], fo = facts[3 * g + 2];
                    int kps = fp * ECONST + fs;
                    int kpo = fp * ECONST + fo;
                    vps[i] = ((unsigned)kps << 11) | (unsigned)fo;
                    vpo[i] = ((unsigned)kpo << 11) | (unsigned)fs;
                    atomicAdd(&cnt[kps >> 8], 1);
                    atomicAdd(&cnt[NBIN + (kpo >> 8)], 1);
                }
            }
            __syncthreads();

            // wave-shuffle exclusive scan of cnt -> lbase, cur
            {
                int lane = t & 63, w = t >> 6;
                int c = (t < NBIN2) ? cnt[t] : 0;
                int inc = c;
                for (int d = 1; d < 64; d <<= 1) {
                    int v = __shfl_up(inc, d);
                    if (lane >= d) inc += v;
                }
                if (lane == 63) wsum[w] = inc;
                __syncthreads();
                if (t < NBIN2) {
                    int wbase = 0;
                    for (int i = 0; i < w; ++i) wbase += wsum[i];
                    int excl = wbase + inc - c;
                    lbase[t] = excl;
                    cur[t]   = excl;
                }
            }
            __syncthreads();
            for (int i = t; i < NBIN2; i += BLOCK_THREADS) {
                int c = cnt[i];
                base[i] = c ? atomicAdd(&bincur[i], c) : 0;
            }
            __syncthreads();

            #pragma unroll
            for (int i = 0; i < FPT; ++i) {
                if (i >= myN) break;
                unsigned ps = vps[i];
                int pos = atomicAdd(&cur[ps >> 19], 1);
                ordered[pos] = ps;
                unsigned po = vpo[i];
                pos = atomicAdd(&cur[NBIN + (po >> 19)], 1);
                ordered[pos] = (1u << 28) | po;
            }
            __syncthreads();

            int n2 = 2 * n;
            for (int j = t; j < n2; j += BLOCK_THREADS) {
                unsigned v = ordered[j];
                int cbin = (int)((v >> 19) & 511u) + ((v >> 28) ? NBIN : 0);
                int pos  = base[cbin] + (j - lbase[cbin]);
                if (pos < CAP) slab[(size_t)cbin * CAP + pos] = v & 0x0FFFFFFFu;
            }
            __syncthreads();
        }
    }
    grid.sync();

    // ---- phase 2: binsort — 4 virtual 256-thread groups per block ----
    {
        int q  = t >> 8;                   // quarter 0..3
        int tq = t & 255;
        unsigned char* segp = smem + q * SEGSZ;
        unsigned short* outv  = (unsigned short*)segp;        // 12288 B
        unsigned char*  keyof = segp + 2 * CAP;               // 6144 B
        int* hist  = (int*)(segp + 3 * CAP);                  // 1024 B
        int* sbase = hist + KPB;                              // 1024 B
        int* wsum4 = sbase + KPB;                             // 16 B
        int* red   = wsum4 + 4;                               // 16 B

        int wg  = bid * 4 + q;             // 0..1023; valid if < NBIN2
        bool vw = (wg < NBIN2);
        int csr = (vw && wg < NBIN) ? 0 : 1;
        int b   = vw ? (wg - csr * NBIN) : 0;
        const int* curbase = bincur + csr * NBIN;
        int gofs = csr ? (F + 64) : 0;
        int lane = tq & 63, w = tq >> 6;

        // compacted base = prefix sum of this CSR's cursors for bins < b
        int s = 0;
        for (int i = tq; i < b; i += KPB) s += curbase[i];
        for (int d = 1; d < 64; d <<= 1) s += __shfl_xor(s, d);
        if (lane == 0) red[w] = s;
        __syncthreads();
        int start = red[0] + red[1] + red[2] + red[3];

        int key0 = b * KPB;
        int len  = vw ? min(curbase[b], CAP) : 0;
        const unsigned* src = slab + (size_t)(vw ? wg : 0) * CAP;

        hist[tq] = 0;
        __syncthreads();

        for (int i = tq; i < len; i += KPB)
            atomicAdd(&hist[(int)(src[i] >> 11) - key0], 1);
        __syncthreads();

        int c = hist[tq];
        int inc = c;
        for (int d = 1; d < 64; d <<= 1) {
            int v = __shfl_up(inc, d);
            if (lane >= d) inc += v;
        }
        if (lane == 63) wsum4[w] = inc;
        __syncthreads();
        int wbase = 0;
        for (int i = 0; i < w; ++i) wbase += wsum4[i];
        int excl = wbase + inc - c;
        int gk = key0 + tq;
        if (vw && gk < NKEY)
            qtab[csr * NKEY + gk] =
                ((unsigned)(gofs + start + excl) << 7) | (unsigned)min(c, MCONST);
        sbase[tq] = excl;
        hist[tq]  = excl;
        __syncthreads();

        for (int i = tq; i < len; i += KPB) {
            unsigned v = src[i];
            int lk  = (int)(v >> 11) - key0;
            int pos = atomicAdd(&hist[lk], 1);
            outv[pos]  = (unsigned short)(v & 2047u);
            keyof[pos] = (unsigned char)lk;
        }
        __syncthreads();

        for (int pos = tq; pos < len; pos += KPB) {
            unsigned short v = outv[pos];
            int lk = (int)keyof[pos];
            int s0 = sbase[lk];
            int e0 = hist[lk];
            int rank = 0;
            for (int j = s0; j < e0; ++j) {
                unsigned short wv = outv[j];
                rank += (wv < v) || (wv == v && j < pos);
            }
            int gpos = start + s0 + rank;
            dataA[gofs + gpos] = v;
            if (gpos == F - 1) {
                for (int j = 0; j < 64; ++j) dataA[gofs + F + j] = v;
            }
        }
    }
    grid.sync();

    // ---- phase 3: queries (R19 body, grid-stride) ----
    {
        int gwave  = (bid * BLOCK_THREADS + t) >> 6;
        int lane   = t & 63;
        int nwaves = (GRID_BLOCKS * BLOCK_THREADS) >> 6;   // 4096
        int grp = lane >> 4;
        int sl  = (lane & 15) * 4;

        for (int qb = gwave * 64; qb < N; qb += nwaves * 64) {
            int q = qb + lane;
            unsigned pk = 0;
            if (q < N) {
                int idx = ((dir[q] != 0) ? NKEY : 0) + preds[q] * ECONST + bound[q];
                pk = qtab[idx];
            }
            int nq = min(64, N - qb);
            for (int j4 = 0; j4 < nq; j4 += 4) {
                int j = j4 + grp;
                unsigned pj = (unsigned)__shfl((int)pk, j);
                if (j < nq) {
                    int c = (int)(pj & 127u);
                    int s = (int)(pj >> 7);
                    ivec4 cv, vv;
                    cv.x = (int)dataA[s + sl];
                    cv.y = (int)dataA[s + sl + 1];
                    cv.z = (int)dataA[s + sl + 2];
                    cv.w = (int)dataA[s + sl + 3];
                    vv.x = (sl     < c) ? 1 : 0;
                    vv.y = (sl + 1 < c) ? 1 : 0;
                    vv.z = (sl + 2 < c) ? 1 : 0;
                    vv.w = (sl + 3 < c) ? 1 : 0;
                    size_t o = (size_t)(qb + j) * MCONST + sl;
                    __builtin_nontemporal_store(cv, (ivec4*)&cand[o]);
                    __builtin_nontemporal_store(vv, (ivec4*)&valid[o]);
                }
            }
        }
    }
}

// ---------------------------------------------------------------------------
extern "C" void kernel_launch(void* const* d_in, const int* in_sizes, int n_in,
                              void* d_out, int out_size, void* d_ws, size_t ws_size,
                              hipStream_t stream) {
    const int* facts = (const int*)d_in[0];
    const int* preds = (const int*)d_in[1];
    const int* bound = (const int*)d_in[2];
    const int* dir   = (const int*)d_in[3];
    int F = in_sizes[0] / 3;
    int N = in_sizes[1];

    // Workspace layout (int32 units)
    int* ws        = (int*)d_ws;
    unsigned* qtab = (unsigned*)ws;              // 2*NKEY
    int* bincur    = ws + 2 * NKEY;              // NBIN2
    int* pad       = bincur + NBIN2;
    size_t ofs = (size_t)(pad - ws);
    ofs = (ofs + 3) & ~(size_t)3;                // 16B-align
    unsigned short* dataA = (unsigned short*)(ws + ofs);          // 2F+128 u16
    unsigned* slab = (unsigned*)(dataA + 2 * (size_t)F + 128);    // [NBIN2][CAP]

    int* cand  = (int*)d_out;
    int* valid = cand + (size_t)N * MCONST;

    void* args[] = {
        (void*)&facts, (void*)&preds, (void*)&bound, (void*)&dir,
        (void*)&bincur, (void*)&slab, (void*)&qtab, (void*)&dataA,
        (void*)&cand, (void*)&valid, (void*)&F, (void*)&N
    };
    hipLaunchCooperativeKernel((const void*)fused_kernel,
                               dim3(GRID_BLOCKS), dim3(BLOCK_THREADS),
                               args, 0, stream);
}

// Round 21
// 135.437 us; speedup vs baseline: 1.5671x; 1.5671x over previous
//
#include <hip/hip_runtime.h>

#define PCONST 50
#define ECONST 2000
#define MCONST 64
#define NKEY   (PCONST * ECONST)          // 100000 keys per CSR
#define KPB    256                        // keys per bin
#define NBIN   ((NKEY + KPB - 1) / KPB)   // 391 bins per CSR
#define NBIN2  (2 * NBIN)                 // 782
#define SC_THREADS 1024
#define SC_CHUNK   8192                   // facts per block = 8/thread -> 84B runs/bin
#define FPT    (SC_CHUNK / SC_THREADS)    // 8
#define CAP    6144                       // bin capacity (mean 5115, +14 sigma, fixed seed)

typedef int ivec4 __attribute__((ext_vector_type(4)));   // nontemporal-store-compatible

// ---------------------------------------------------------------------------
// 1) Split-CSR block-sorted slab scatter: blockIdx.y = CSR (0: key=fp*E+fs
//    val=fo; 1: key=fp*E+fo val=fs). Each block sorts ONE CSR of one
//    8192-fact chunk -> ordered 32KB + 391-entry tables = 39KB LDS ->
//    2-3 resident blocks/CU (vs R19's 1) with the SAME 21-elem runs
//    (write-amp unchanged). Cost: facts streamed once per CSR (2x total).
// ---------------------------------------------------------------------------
__global__ void __launch_bounds__(SC_THREADS)
scatter_sort(const int* __restrict__ facts,
             int* __restrict__ bincur,
             unsigned* __restrict__ slab, int F) {
    __shared__ unsigned ordered[SC_CHUNK];       // 32 KB
    __shared__ int cnt[NBIN];
    __shared__ int lbase[NBIN];
    __shared__ int cur[NBIN];
    __shared__ int base[NBIN];
    __shared__ int wsum[16];

    int t   = threadIdx.x;
    int csr = blockIdx.y;
    int blockStart = blockIdx.x * SC_CHUNK;
    int n = min(SC_CHUNK, F - blockStart);
    if (n <= 0) return;

    for (int i = t; i < NBIN; i += SC_THREADS) cnt[i] = 0;
    __syncthreads();

    int myBase = blockStart + t * FPT;
    int myN = F - myBase;
    myN = (myN < 0) ? 0 : ((myN > FPT) ? FPT : myN);

    unsigned vpk[FPT];                           // packed (key<<11|val), this CSR

    // ---- pass A: load + pack + count (one atomic per fact) ----
    if (myN == FPT) {
        const int4* p = (const int4*)(facts + 3 * myBase);   // 16B-aligned
        int4 w0 = p[0], w1 = p[1], w2 = p[2], w3 = p[3], w4 = p[4], w5 = p[5];
        int fp[FPT] = { w0.x, w0.w, w1.z, w2.y, w3.x, w3.w, w4.z, w5.y };
        int fs[FPT] = { w0.y, w1.x, w1.w, w2.z, w3.y, w4.x, w4.w, w5.z };
        int fo[FPT] = { w0.z, w1.y, w2.x, w2.w, w3.z, w4.y, w5.x, w5.w };
        #pragma unroll
        for (int i = 0; i < FPT; ++i) {
            int key = fp[i] * ECONST + (csr ? fo[i] : fs[i]);
            int val = csr ? fs[i] : fo[i];
            vpk[i] = ((unsigned)key << 11) | (unsigned)val;
            atomicAdd(&cnt[key >> 8], 1);
        }
    } else {
        for (int i = 0; i < myN; ++i) {
            int g = myBase + i;
            int fp = facts[3 * g], fs = facts[3 * g + 1], fo = facts[3 * g + 2];
            int key = fp * ECONST + (csr ? fo : fs);
            int val = csr ? fs : fo;
            vpk[i] = ((unsigned)key << 11) | (unsigned)val;
            atomicAdd(&cnt[key >> 8], 1);
        }
    }
    __syncthreads();

    // ---- wave-shuffle exclusive scan of cnt[0..391) -> lbase, cur ----
    {
        int lane = t & 63, w = t >> 6;
        int c = (t < NBIN) ? cnt[t] : 0;
        int inc = c;
        for (int d = 1; d < 64; d <<= 1) {
            int v = __shfl_up(inc, d);
            if (lane >= d) inc += v;
        }
        if (lane == 63) wsum[w] = inc;
        __syncthreads();
        if (t < NBIN) {
            int wbase = 0;
            for (int i = 0; i < w; ++i) wbase += wsum[i];
            int excl = wbase + inc - c;
            lbase[t] = excl;
            cur[t]   = excl;
            int cc = c;
            base[t] = cc ? atomicAdd(&bincur[csr * NBIN + t], cc) : 0;
        }
    }
    __syncthreads();

    // ---- pass B: place into bin-ordered LDS ----
    #pragma unroll
    for (int i = 0; i < FPT; ++i) {
        if (i >= myN) break;
        unsigned v = vpk[i];
        int pos = atomicAdd(&cur[v >> 19], 1);
        ordered[pos] = v;
    }
    __syncthreads();

    // ---- write-out: flat, lane-coalesced (consecutive j -> consecutive addr)
    for (int j = t; j < n; j += SC_THREADS) {
        unsigned v = ordered[j];
        int bin = (int)(v >> 19);                // == key >> 8, 0..390
        int pos = base[bin] + (j - lbase[bin]);
        if (pos < CAP) slab[(size_t)(csr * NBIN + bin) * CAP + pos] = v;
    }
}

// ---------------------------------------------------------------------------
// 2) Per-bin counting sort, element-parallel rank finish (R19 verbatim).
// ---------------------------------------------------------------------------
__global__ void binsort_kernel(const int* __restrict__ bincur,
                               const unsigned* __restrict__ slab,
                               unsigned* __restrict__ qtab,        // [2*NKEY]
                               unsigned short* __restrict__ dataA, // [2F+128]
                               int F) {
    __shared__ unsigned short outv[CAP];   // 12 KB (placed, unsorted-in-key)
    __shared__ unsigned char  keyof[CAP];  // 6 KB
    __shared__ int hist[KPB];              // counts -> excl -> end cursors
    __shared__ int sbase[KPB];             // excl bases (stable copy)
    __shared__ int wsum[4];
    __shared__ int red[4];

    int wg = blockIdx.x;
    int csr = (wg < NBIN) ? 0 : 1;
    int b   = wg - csr * NBIN;
    const int* curbase = bincur + csr * NBIN;
    int gofs = csr ? (F + 64) : 0;               // po region after ps pad
    int t = threadIdx.x;
    int lane = t & 63, w = t >> 6;

    // compacted base = sum of this CSR's cursors for bins < b
    int s = 0;
    for (int i = t; i < b; i += KPB) s += curbase[i];
    for (int d = 1; d < 64; d <<= 1) s += __shfl_xor(s, d);
    if (lane == 0) red[w] = s;
    __syncthreads();
    int start = red[0] + red[1] + red[2] + red[3];

    int key0 = b * KPB;
    int len  = min(curbase[b], CAP);
    const unsigned* src = slab + (size_t)wg * CAP;

    hist[t] = 0;
    __syncthreads();

    // ---- pass 1: histogram (coalesced slab read) ----
    for (int i = t; i < len; i += KPB)
        atomicAdd(&hist[(int)(src[i] >> 11) - key0], 1);
    __syncthreads();

    // ---- wave-shuffle exclusive scan; qtab descriptor; stable bases ----
    int c = hist[t];
    int inc = c;
    for (int d = 1; d < 64; d <<= 1) {
        int v = __shfl_up(inc, d);
        if (lane >= d) inc += v;
    }
    if (lane == 63) wsum[w] = inc;
    __syncthreads();
    int wbase = 0;
    for (int i = 0; i < w; ++i) wbase += wsum[i];
    int excl = wbase + inc - c;
    int gk = key0 + t;
    if (gk < NKEY)
        qtab[csr * NKEY + gk] =
            ((unsigned)(gofs + start + excl) << 7) | (unsigned)min(c, MCONST);
    sbase[t] = excl;
    hist[t]  = excl;                              // own-slot overwrite only
    __syncthreads();

    // ---- pass 2: placement (slab re-read, L2-hot); record key per slot ----
    for (int i = t; i < len; i += KPB) {
        unsigned v = src[i];
        int lk  = (int)(v >> 11) - key0;
        int pos = atomicAdd(&hist[lk], 1);
        outv[pos]  = (unsigned short)(v & 2047u);
        keyof[pos] = (unsigned char)lk;
    }
    __syncthreads();                              // hist[lk] now = run end

    // ---- pass 3: element-parallel rank + direct global store ----
    for (int pos = t; pos < len; pos += KPB) {
        unsigned short v = outv[pos];
        int lk = (int)keyof[pos];
        int s0 = sbase[lk];
        int e0 = hist[lk];
        int rank = 0;
        for (int j = s0; j < e0; ++j) {           // independent, pipelined reads
            unsigned short wv = outv[j];
            rank += (wv < v) || (wv == v && j < pos);
        }
        int gpos = start + s0 + rank;
        dataA[gofs + gpos] = v;
        if (gpos == F - 1) {                      // clip pad: 64 copies of last
            for (int j = 0; j < 64; ++j) dataA[gofs + F + j] = v;
        }
    }
}

// ---------------------------------------------------------------------------
// 3) Queries: 4 per wave-iteration, 16 lanes x 4 slots; ONE random qtab
//    gather per query; pad makes gathers clip-free (R19 verbatim).
// ---------------------------------------------------------------------------
__global__ void query_kernel(const int* __restrict__ preds,
                             const int* __restrict__ bound,
                             const int* __restrict__ dir,
                             const unsigned* __restrict__ qtab,
                             const unsigned short* __restrict__ dataA,
                             int* __restrict__ cand,
                             int* __restrict__ valid, int N) {
    int gwave  = (blockIdx.x * blockDim.x + threadIdx.x) >> 6;
    int lane   = threadIdx.x & 63;
    int nwaves = (gridDim.x * blockDim.x) >> 6;
    int grp = lane >> 4;             // which of the 4 queries in this iteration
    int sl  = (lane & 15) * 4;       // slot base 0..60

    for (int qb = gwave * 64; qb < N; qb += nwaves * 64) {
        int q = qb + lane;
        unsigned pk = 0;
        if (q < N) {
            int idx = ((dir[q] != 0) ? NKEY : 0) + preds[q] * ECONST + bound[q];
            pk = qtab[idx];
        }
        int nq = min(64, N - qb);
        for (int j4 = 0; j4 < nq; j4 += 4) {
            int j = j4 + grp;
            unsigned pj = (unsigned)__shfl((int)pk, j);
            if (j < nq) {
                int c = (int)(pj & 127u);
                int s = (int)(pj >> 7);
                ivec4 cv, vv;
                cv.x = (int)dataA[s + sl];
                cv.y = (int)dataA[s + sl + 1];
                cv.z = (int)dataA[s + sl + 2];
                cv.w = (int)dataA[s + sl + 3];
                vv.x = (sl     < c) ? 1 : 0;
                vv.y = (sl + 1 < c) ? 1 : 0;
                vv.z = (sl + 2 < c) ? 1 : 0;
                vv.w = (sl + 3 < c) ? 1 : 0;
                size_t o = (size_t)(qb + j) * MCONST + sl;   // 16B-aligned (sl%4==0)
                __builtin_nontemporal_store(cv, (ivec4*)&cand[o]);
                __builtin_nontemporal_store(vv, (ivec4*)&valid[o]);
            }
        }
    }
}

// ---------------------------------------------------------------------------
extern "C" void kernel_launch(void* const* d_in, const int* in_sizes, int n_in,
                              void* d_out, int out_size, void* d_ws, size_t ws_size,
                              hipStream_t stream) {
    const int* facts = (const int*)d_in[0];
    const int* preds = (const int*)d_in[1];
    const int* bound = (const int*)d_in[2];
    const int* dir   = (const int*)d_in[3];
    int F = in_sizes[0] / 3;
    int N = in_sizes[1];

    // Workspace layout (int32 units)
    int* ws        = (int*)d_ws;
    unsigned* qtab = (unsigned*)ws;              // 2*NKEY
    int* bincur    = ws + 2 * NKEY;              // NBIN2
    int* pad       = bincur + NBIN2;
    size_t ofs = (size_t)(pad - ws);
    ofs = (ofs + 3) & ~(size_t)3;                // 16B-align
    unsigned short* dataA = (unsigned short*)(ws + ofs);          // 2F+128 u16
    unsigned* slab = (unsigned*)(dataA + 2 * (size_t)F + 128);    // [NBIN2][CAP]

    hipMemsetAsync(bincur, 0, (size_t)NBIN2 * sizeof(int), stream);

    int nChunks = (F + SC_CHUNK - 1) / SC_CHUNK;
    dim3 sg(nChunks, 2);
    scatter_sort<<<sg, SC_THREADS, 0, stream>>>(facts, bincur, slab, F);
    binsort_kernel<<<NBIN2, KPB, 0, stream>>>(bincur, slab, qtab, dataA, F);

    int* cand  = (int*)d_out;
    int* valid = cand + (size_t)N * MCONST;
    int qBlocks = (N / 64 + 3) / 4 + 1;          // ~1954 blocks, 4 waves each
    query_kernel<<<qBlocks, 256, 0, stream>>>(
        preds, bound, dir, qtab, dataA, cand, valid, N);
}